// Round 6
// baseline (366.223 us; speedup 1.0000x reference)
//
#include <hip/hip_runtime.h>

// LSTM round 6: in-wave recurrence, 4 batches/wave, 2048 waves = 2 waves/SIMD.
// B=8192, T=512, IN=5, H=32. No LDS tiles, no barriers.
// gates_T[128 x 16col] = Wext * hext^T, B cols = 4 batches dup 4x (col&3).
// Lane (col,kg): batch=col&3, cq=col>>2 -> jhigh=cq>>1, rp=cq&1 ->
// owns 2 cells j0,j0+1 with j0 = 16*jhigh + 4*kg + 2*rp. Zero cell redundancy:
// per-SIMD transcendental work constant vs round 5, but 2 waves hide latency.
// h^T B-frag rebuilt with 4 __shfl; x split hi/lo via v_cvt_pk_bf16_f32.

typedef __attribute__((ext_vector_type(8))) short short8;
typedef __attribute__((ext_vector_type(4))) float f32x4;
typedef __attribute__((ext_vector_type(4))) unsigned int u32x4;

static constexpr int BB  = 8192;
static constexpr int TT  = 512;
static constexpr int NIN = 5;
static constexpr int HH  = 32;

__device__ __forceinline__ unsigned short bf_rne(float f) {
    unsigned int u = __float_as_uint(f);
    u = (u + 0x7FFFu + ((u >> 16) & 1u)) >> 16;
    return (unsigned short)u;
}
__device__ __forceinline__ float bf_f32(unsigned short h) {
    return __uint_as_float((unsigned int)h << 16);
}
__device__ __forceinline__ float fast_sigmoid(float x) {
    float e = __builtin_amdgcn_exp2f(-1.4426950408889634f * x);
    return __builtin_amdgcn_rcpf(1.0f + e);
}
__device__ __forceinline__ float fast_tanh(float x) {
    float e = __builtin_amdgcn_exp2f(2.8853900817779268f * x);
    return 1.0f - 2.0f * __builtin_amdgcn_rcpf(1.0f + e);
}
// D.lo16 = bf16(a), D.hi16 = bf16(b)
__device__ __forceinline__ unsigned int cvt_pk_bf16(float a, float b) {
    unsigned int r;
    asm("v_cvt_pk_bf16_f32 %0, %1, %2" : "=v"(r) : "v"(a), "v"(b));
    return r;
}

__global__ __launch_bounds__(64, 2) void lstm_wave4(
    const float* __restrict__ x,     // [B, T, 5]
    const float* __restrict__ W_ih,  // [128, 5]
    const float* __restrict__ W_hh,  // [128, 32]
    const float* __restrict__ b_ih,  // [128]
    const float* __restrict__ b_hh,  // [128]
    const float* __restrict__ W_fc,  // [1, 32]
    const float* __restrict__ b_fc,  // [1]
    float* __restrict__ out)         // [B]
{
    const int lane  = threadIdx.x & 63;
    const int col   = lane & 15;
    const int kg    = lane >> 4;
    const int bloc  = col & 3;       // batch 0..3 (cols duplicate 4x)
    const int cq    = col >> 2;      // which 2 of the 8 candidate cells
    const int jhigh = cq >> 1;       // tile parity (j<16 vs j>=16)
    const int rp    = cq & 1;        // reg pair (0,1) vs (2,3)
    const int b0    = blockIdx.x * 4;
    const int j0    = 16 * jhigh + 4 * kg + 2 * rp;  // first owned j

    // ---- A-fragments (loop-invariant): tile t4 rows gr=16*t4+col, k=kg*8+e.
    // K-tile0 = h (Whh hi/lo). K-tile1 (x): kg0={Wih_hi,bias_hi},
    // kg1={Wih_hi,bias_lo}, kg2={Wih_lo}, kg3=0.
    short8 Ahh_hi[8], Ahh_lo[8], Ax[8];
#pragma unroll
    for (int t4 = 0; t4 < 8; ++t4) {
        const int gr = 16 * t4 + col;
#pragma unroll
        for (int e = 0; e < 8; ++e) {
            float wv = W_hh[gr * HH + kg * 8 + e];
            unsigned short hi = bf_rne(wv);
            Ahh_hi[t4][e] = (short)hi;
            Ahh_lo[t4][e] = (short)bf_rne(wv - bf_f32(hi));
        }
        float bias = b_ih[gr] + b_hh[gr];
        unsigned short bh_ = bf_rne(bias);
        unsigned short bl_ = bf_rne(bias - bf_f32(bh_));
        short8 v;
#pragma unroll
        for (int e = 0; e < 8; ++e) v[e] = 0;
        if (kg == 0 || kg == 1) {
#pragma unroll
            for (int e = 0; e < NIN; ++e) v[e] = (short)bf_rne(W_ih[gr * NIN + e]);
            v[5] = (short)((kg == 0) ? bh_ : bl_);
        } else if (kg == 2) {
#pragma unroll
            for (int e = 0; e < NIN; ++e) {
                float wv = W_ih[gr * NIN + e];
                unsigned short h2 = bf_rne(wv);
                v[e] = (short)bf_rne(wv - bf_f32(h2));
            }
        }
        Ax[t4] = v;
    }

    // ---- x loader: lanes 0..19 own (batch=lane/5, elem=lane%5) ----
    const int xb = (lane / 5 < 4) ? (lane / 5) : 3;
    int xe = lane - 5 * xb; if (xe > 4) xe = 4;
    const float* px = x + ((size_t)(b0 + xb) * TT) * NIN + xe;

    const unsigned shx  = (kg == 1) ? 16u : 0u;              // hi vs lo extract
    const unsigned one5 = (kg < 2) ? (0x3F80u << 16) : 0u;   // 1.0 in slot 5

    // ---- bh shuffle sources: word w holds h[8kg+2w], h[8kg+2w+1] of my batch ----
    int src0, src1, src2, src3;
    {
        int s[4];
#pragma unroll
        for (int w = 0; w < 4; ++w) {
            const int j0s = 8 * kg + 2 * w;
            const int jhs = j0s >> 4;
            const int rem = j0s & 15;
            const int kgs = rem >> 2;
            const int rps = (rem >> 1) & 1;
            s[w] = 16 * kgs + 4 * (2 * jhs + rps) + bloc;
        }
        src0 = s[0]; src1 = s[1]; src2 = s[2]; src3 = s[3];
    }

    // x for t=0
    float xv = px[0]; px += NIN;
    unsigned int xpk;
    {
        unsigned int t0 = cvt_pk_bf16(xv, xv);
        float hif = __uint_as_float(t0 << 16);
        xpk = cvt_pk_bf16(xv, xv - hif);   // lo16 = hi-part, hi16 = lo-part
    }

    unsigned int bh0 = 0, bh1 = 0, bh2 = 0, bh3 = 0;  // h^T frag (h=0)
    float cA = 0.f, cB = 0.f, hA = 0.f, hB = 0.f;
    const f32x4 z = {0.f, 0.f, 0.f, 0.f};

#pragma unroll 1
    for (int t = 0; t < TT; ++t) {
        // (1) prefetch next x
        float xvn = xv;
        if (t + 1 < TT) { xvn = px[0]; px += NIN; }

        // (2) bx: broadcast my batch's 5 packed x words
        unsigned int p0x = (unsigned)__shfl((int)xpk, 5 * bloc + 0, 64);
        unsigned int p1x = (unsigned)__shfl((int)xpk, 5 * bloc + 1, 64);
        unsigned int p2x = (unsigned)__shfl((int)xpk, 5 * bloc + 2, 64);
        unsigned int p3x = (unsigned)__shfl((int)xpk, 5 * bloc + 3, 64);
        unsigned int p4x = (unsigned)__shfl((int)xpk, 5 * bloc + 4, 64);
        unsigned int a0 = (p0x >> shx) & 0xFFFFu;
        unsigned int a1 = (p1x >> shx) & 0xFFFFu;
        unsigned int a2 = (p2x >> shx) & 0xFFFFu;
        unsigned int a3 = (p3x >> shx) & 0xFFFFu;
        unsigned int a4 = (p4x >> shx) & 0xFFFFu;
        u32x4 bxu = {a0 | (a1 << 16), a2 | (a3 << 16), a4 | one5, 0u};
        short8 bx = __builtin_bit_cast(short8, bxu);
        u32x4 bhu = {bh0, bh1, bh2, bh3};
        short8 bh = __builtin_bit_cast(short8, bhu);

        // (3) 24 MFMAs, 8 independent 3-chains
        f32x4 acc[8];
#pragma unroll
        for (int t4 = 0; t4 < 8; ++t4)
            acc[t4] = __builtin_amdgcn_mfma_f32_16x16x32_bf16(Ahh_lo[t4], bh, z, 0, 0, 0);
#pragma unroll
        for (int t4 = 0; t4 < 8; ++t4)
            acc[t4] = __builtin_amdgcn_mfma_f32_16x16x32_bf16(Ahh_hi[t4], bh, acc[t4], 0, 0, 0);
#pragma unroll
        for (int t4 = 0; t4 < 8; ++t4)
            acc[t4] = __builtin_amdgcn_mfma_f32_16x16x32_bf16(Ax[t4], bx, acc[t4], 0, 0, 0);

        // (4) two cells: gate g tile = 2g+jhigh, reg = 2*rp + d (literal idx)
        float giA = jhigh ? (rp ? acc[1][2] : acc[1][0]) : (rp ? acc[0][2] : acc[0][0]);
        float gfA = jhigh ? (rp ? acc[3][2] : acc[3][0]) : (rp ? acc[2][2] : acc[2][0]);
        float ggA = jhigh ? (rp ? acc[5][2] : acc[5][0]) : (rp ? acc[4][2] : acc[4][0]);
        float goA = jhigh ? (rp ? acc[7][2] : acc[7][0]) : (rp ? acc[6][2] : acc[6][0]);
        float giB = jhigh ? (rp ? acc[1][3] : acc[1][1]) : (rp ? acc[0][3] : acc[0][1]);
        float gfB = jhigh ? (rp ? acc[3][3] : acc[3][1]) : (rp ? acc[2][3] : acc[2][1]);
        float ggB = jhigh ? (rp ? acc[5][3] : acc[5][1]) : (rp ? acc[4][3] : acc[4][1]);
        float goB = jhigh ? (rp ? acc[7][3] : acc[7][1]) : (rp ? acc[6][3] : acc[6][1]);

        {
            float iv = fast_sigmoid(giA);
            float fv = fast_sigmoid(gfA);
            float gv = fast_tanh(ggA);
            float ov = fast_sigmoid(goA);
            cA = fv * cA + iv * gv;
            hA = ov * fast_tanh(cA);
        }
        {
            float iv = fast_sigmoid(giB);
            float fv = fast_sigmoid(gfB);
            float gv = fast_tanh(ggB);
            float ov = fast_sigmoid(goB);
            cB = fv * cB + iv * gv;
            hB = ov * fast_tanh(cB);
        }

        // (5) pack h pair; rebuild bh for t+1 with 4 shfl
        unsigned int p = cvt_pk_bf16(hA, hB);    // lo16 = h[j0], hi16 = h[j0+1]
        bh0 = (unsigned)__shfl((int)p, src0, 64);
        bh1 = (unsigned)__shfl((int)p, src1, 64);
        bh2 = (unsigned)__shfl((int)p, src2, 64);
        bh3 = (unsigned)__shfl((int)p, src3, 64);

        // (6) convert next x (hi/lo split via cvt_pk)
        {
            unsigned int t0 = cvt_pk_bf16(xvn, xvn);
            float hif = __uint_as_float(t0 << 16);
            xpk = cvt_pk_bf16(xvn, xvn - hif);
        }
        xv = xvn;
    }

    // ---- head: out[b] = sum_j h[b][j]*W_fc[j] + b_fc ----
    float v = hA * W_fc[j0] + hB * W_fc[j0 + 1];
    v += __shfl_xor(v, 4);
    v += __shfl_xor(v, 8);
    v += __shfl_xor(v, 16);
    v += __shfl_xor(v, 32);
    if (lane < 4) out[b0 + lane] = v + b_fc[0];
}

extern "C" void kernel_launch(void* const* d_in, const int* in_sizes, int n_in,
                              void* d_out, int out_size, void* d_ws, size_t ws_size,
                              hipStream_t stream) {
    const float* x    = (const float*)d_in[0];
    const float* W_ih = (const float*)d_in[1];
    const float* W_hh = (const float*)d_in[2];
    const float* b_ih = (const float*)d_in[3];
    const float* b_hh = (const float*)d_in[4];
    const float* W_fc = (const float*)d_in[5];
    const float* b_fc = (const float*)d_in[6];
    float* out = (float*)d_out;

    lstm_wave4<<<dim3(BB / 4), dim3(64), 0, stream>>>(
        x, W_ih, W_hh, b_ih, b_hh, W_fc, b_fc, out);
}